// Round 11
// baseline (1864.914 us; speedup 1.0000x reference)
//
#include <hip/hip_runtime.h>
#include <cstdint>

#define B_ 64
#define N_ 4096
#define D_ 256
#define NS_ 8
#define HID_ 512
#define EPS_ 1e-8f
#define SCALE_ 0.0625f
#define LN_EPS_ 1e-5f

typedef _Float16 f16;
typedef __attribute__((ext_vector_type(4))) _Float16 f16x4;
typedef __attribute__((ext_vector_type(8))) _Float16 f16x8;

// ---------------- transpose GRU weights [768][256] -> [256][768] ----------------
__global__ void k_transpose(const float* __restrict__ wi, const float* __restrict__ wh,
                            float* __restrict__ wiT, float* __restrict__ whT) {
  int idx = blockIdx.x * 256 + threadIdx.x;      // 0..196607
  int o = idx >> 8;                              // 0..767
  int d = idx & 255;
  wiT[d * 768 + o] = wi[idx];
  whT[d * 768 + o] = wh[idx];
}

// ---------------- transpose Wk [e][d] -> WkX [d][e] (fp32) ----------------
__global__ void k_wkx(const float* __restrict__ Wk, float* __restrict__ WkX) {
  int e = blockIdx.x, d = threadIdx.x;
  WkX[d * 256 + e] = Wk[e * 256 + d];   // read coalesced, write scattered (256 KB, once)
}

// ---------------- M[c][e] = SCALE * sum_d Wq[c][d] * Wk[e][d]  (= Wq@Wk^T) ----------------
__global__ __launch_bounds__(256) void k_m(const float* __restrict__ Wq,
                                           const float* __restrict__ WkX,
                                           float* __restrict__ M) {
  __shared__ float wq[256];
  const int c = blockIdx.x, e = threadIdx.x;
  wq[e] = Wq[c * 256 + e];
  __syncthreads();
  float a0 = 0.f, a1 = 0.f, a2 = 0.f, a3 = 0.f;
  #pragma unroll 8
  for (int d = 0; d < 256; d += 4) {
    a0 = fmaf(wq[d],     WkX[(d)     * 256 + e], a0);
    a1 = fmaf(wq[d + 1], WkX[(d + 1) * 256 + e], a1);
    a2 = fmaf(wq[d + 2], WkX[(d + 2) * 256 + e], a2);
    a3 = fmaf(wq[d + 3], WkX[(d + 3) * 256 + e], a3);
  }
  M[c * 256 + e] = (a0 + a1 + a2 + a3) * SCALE_;
}

// ---------------- slots init: mu + exp(logsigma)*noise ----------------
__global__ void k_init_slots(const float* __restrict__ noise, const float* __restrict__ mu,
                             const float* __restrict__ ls, float* __restrict__ slots) {
  int idx = blockIdx.x * 256 + threadIdx.x;      // 0..131071
  int d = idx & 255;
  slots[idx] = mu[d] + __expf(ls[d]) * noise[idx];
}

// ---------------- xh = LN(inputs) as fp16 (wave per row) ----------------
__global__ __launch_bounds__(256) void k_xh(const float* __restrict__ in,
    const float* __restrict__ g, const float* __restrict__ bb, f16* __restrict__ xh) {
  const int wave = threadIdx.x >> 6, lane = threadIdx.x & 63;
  const size_t row = (size_t)blockIdx.x * 4 + wave;
  const float* r = in + row * D_;
  float4 a = *(const float4*)(r + lane * 4);
  float s1 = a.x + a.y + a.z + a.w;
  float s2 = a.x * a.x + a.y * a.y + a.z * a.z + a.w * a.w;
  #pragma unroll
  for (int m = 32; m >= 1; m >>= 1) { s1 += __shfl_xor(s1, m, 64); s2 += __shfl_xor(s2, m, 64); }
  const float mean = s1 * (1.f / D_);
  const float rstd = rsqrtf(s2 * (1.f / D_) - mean * mean + LN_EPS_);
  float4 gg = *(const float4*)(g + lane * 4);
  float4 bv = *(const float4*)(bb + lane * 4);
  f16x4 o;
  o[0] = (f16)((a.x - mean) * rstd * gg.x + bv.x);
  o[1] = (f16)((a.y - mean) * rstd * gg.y + bv.y);
  o[2] = (f16)((a.z - mean) * rstd * gg.z + bv.z);
  o[3] = (f16)((a.w - mean) * rstd * gg.w + bv.w);
  *(f16x4*)(xh + row * D_ + lane * 4) = o;
}

// ---------------- qk = LN(slots) @ M + zero ur/asum (once, before iter 0) ----------------
__global__ __launch_bounds__(256) void k_qk(const float* __restrict__ slots,
    const float* __restrict__ g, const float* __restrict__ b,
    const float* __restrict__ M, float* __restrict__ qk,
    float* __restrict__ ur, float* __restrict__ asum) {
  const int row = blockIdx.x;
  const int t = threadIdx.x;
  ur[(size_t)row * D_ + t] = 0.f;
  if (t == 0) asum[row] = 0.f;
  __shared__ float sl[256];
  __shared__ float red1[4], red2[4];
  float val = slots[(size_t)row * D_ + t];
  float s1 = val, s2 = val * val;
  #pragma unroll
  for (int m = 32; m >= 1; m >>= 1) { s1 += __shfl_xor(s1, m, 64); s2 += __shfl_xor(s2, m, 64); }
  int wave = t >> 6, lane = t & 63;
  if (lane == 0) { red1[wave] = s1; red2[wave] = s2; }
  __syncthreads();
  s1 = red1[0] + red1[1] + red1[2] + red1[3];
  s2 = red2[0] + red2[1] + red2[2] + red2[3];
  float mean = s1 * (1.f / D_);
  float rstd = rsqrtf(s2 * (1.f / D_) - mean * mean + LN_EPS_);
  sl[t] = (val - mean) * rstd * g[t] + b[t];
  __syncthreads();
  float a0 = 0.f, a1 = 0.f, a2 = 0.f, a3 = 0.f;
  #pragma unroll 8
  for (int d = 0; d < D_; d += 4) {
    a0 = fmaf(sl[d],     M[(d)     * D_ + t], a0);
    a1 = fmaf(sl[d + 1], M[(d + 1) * D_ + t], a1);
    a2 = fmaf(sl[d + 2], M[(d + 2) * D_ + t], a2);
    a3 = fmaf(sl[d + 3], M[(d + 3) * D_ + t], a3);
  }
  qk[(size_t)row * D_ + t] = a0 + a1 + a2 + a3;
}

// ---------------- fused: dots(qk·xh) + softmax(slots) + renorm-sum + u_raw ----------------
// 256 thr / 128 tokens; lane-pair per token (d split in half, shfl_xor combine).
// Phase B: wave-per-32-tokens, lane-per-d-quad, 8 slots in regs; LDS-atomic combine.
__global__ __launch_bounds__(256) void k_attn_upd(
    const f16* __restrict__ xh, const float* __restrict__ qk,
    float* __restrict__ ur, float* __restrict__ asum) {
  const int b = blockIdx.y;
  const int jt = blockIdx.x * 128;          // 32 chunks of 128 tokens
  const int tid = threadIdx.x;
  const int wave = tid >> 6, lane = tid & 63;
  const int tok = wave * 32 + (lane >> 1);  // block-local token 0..127
  const int half = lane & 1;                // d half: half*128
  __shared__ float wv_s[128 * 9];           // [token][slot], pad 9  (4.6 KB)
  __shared__ float u_acc[NS_ * D_];         // block accumulator     (8 KB)
  const float* qb = qk + (size_t)b * NS_ * D_;  // uniform -> scalar loads

  #pragma unroll
  for (int c = 0; c < 8; ++c) u_acc[tid * 8 + c] = 0.f;

  // ---- phase A: half-dots for my token, then pair-combine ----
  float dots[8] = {0.f, 0.f, 0.f, 0.f, 0.f, 0.f, 0.f, 0.f};
  {
    const f16* xr = xh + ((size_t)b * N_ + jt + tok) * D_ + half * 128;
    const float* qh = qb + half * 128;
    #pragma unroll
    for (int c = 0; c < 4; ++c) {          // 4 chunks of 32 d
      f16x8 kk[4];
      #pragma unroll
      for (int j = 0; j < 4; ++j) kk[j] = *(const f16x8*)(xr + c * 32 + j * 8);
      #pragma unroll
      for (int j = 0; j < 4; ++j) {
        float kf[8];
        #pragma unroll
        for (int e = 0; e < 8; ++e) kf[e] = (float)kk[j][e];
        #pragma unroll
        for (int i = 0; i < 8; ++i) {
          const float* qq = qh + i * D_ + c * 32 + j * 8;
          float acc = dots[i];
          #pragma unroll
          for (int e = 0; e < 8; ++e) acc = fmaf(kf[e], qq[e], acc);
          dots[i] = acc;
        }
      }
    }
  }
  #pragma unroll
  for (int i = 0; i < 8; ++i) dots[i] += __shfl_xor(dots[i], 1, 64);

  // softmax over slots + EPS (lane pairs redundant; even lane writes)
  {
    float m = dots[0];
    #pragma unroll
    for (int i = 1; i < 8; ++i) m = fmaxf(m, dots[i]);
    float e[8], s = 0.f;
    #pragma unroll
    for (int i = 0; i < 8; ++i) { e[i] = __expf(dots[i] - m); s += e[i]; }
    float is = 1.f / s;
    #pragma unroll
    for (int i = 0; i < 8; ++i) {
      float wv = e[i] * is + EPS_;
      if (!half) wv_s[tok * 9 + i] = wv;
      float vv = half ? 0.f : wv;           // count each token once
      #pragma unroll
      for (int mm = 32; mm >= 1; mm >>= 1) vv += __shfl_xor(vv, mm, 64);
      if (lane == 0) atomicAdd(&asum[b * NS_ + i], vv);
    }
  }
  __syncthreads();

  // ---- phase B: wave w -> tokens [w*32, +32); lane -> d quad; 8 slots in regs ----
  {
    const f16* xb = xh + ((size_t)b * N_ + jt + wave * 32) * D_ + lane * 4;
    float acc[8][4] = {};
    #pragma unroll 4
    for (int j = 0; j < 32; ++j) {
      f16x4 vvh = *(const f16x4*)(xb + (size_t)j * D_);
      float vx = (float)vvh[0], vy = (float)vvh[1], vz = (float)vvh[2], vw = (float)vvh[3];
      const float* wr = &wv_s[(wave * 32 + j) * 9];
      #pragma unroll
      for (int i = 0; i < 8; ++i) {
        float w = wr[i];
        acc[i][0] = fmaf(w, vx, acc[i][0]);
        acc[i][1] = fmaf(w, vy, acc[i][1]);
        acc[i][2] = fmaf(w, vz, acc[i][2]);
        acc[i][3] = fmaf(w, vw, acc[i][3]);
      }
    }
    #pragma unroll
    for (int i = 0; i < 8; ++i) {
      float* ua = &u_acc[i * D_ + lane * 4];
      atomicAdd(ua + 0, acc[i][0]);
      atomicAdd(ua + 1, acc[i][1]);
      atomicAdd(ua + 2, acc[i][2]);
      atomicAdd(ua + 3, acc[i][3]);
    }
  }
  __syncthreads();

  // ---- final: one global atomic per (slot, d) cell ----
  {
    const int s = tid >> 5;            // 0..7
    const int d0 = (tid & 31) * 8;     // 0..248
    float* up = ur + ((size_t)b * NS_ + s) * D_ + d0;
    const float* ua = &u_acc[s * D_ + d0];
    #pragma unroll
    for (int c = 0; c < 8; ++c) atomicAdd(up + c, ua[c]);
  }
}

// ---------------- GRU + LN + MLP residual + next-iter qk + accumulator zero ----------------
__global__ __launch_bounds__(256) void k_gru_mlp(
    float* __restrict__ ur, float* __restrict__ asum,
    const float* __restrict__ slots, const float* __restrict__ Wv,
    const float* __restrict__ wiT, const float* __restrict__ whT,
    const float* __restrict__ bi, const float* __restrict__ bh,
    const float* __restrict__ w1, const float* __restrict__ b1,
    const float* __restrict__ w2, const float* __restrict__ b2,
    const float* __restrict__ gf, const float* __restrict__ bf,
    const float* __restrict__ gs, const float* __restrict__ bs,
    const float* __restrict__ M,
    float* __restrict__ out, float* __restrict__ qk) {
  const int row = blockIdx.x;   // 0..511 = b*8+i
  const int t = threadIdx.x;
  __shared__ float urs[256], xs[256], hs[256], ffs[256], hid[512];
  __shared__ float red1[4], red2[4];
  const float hv = slots[(size_t)row * D_ + t];
  const float asv = asum[row];
  urs[t] = ur[(size_t)row * D_ + t];
  // zero accumulators for the NEXT iteration (current values captured above)
  ur[(size_t)row * D_ + t] = 0.f;
  hs[t] = hv;
  __syncthreads();
  if (t == 0) asum[row] = 0.f;
  // updates = (u_raw @ Wv) / asum   (Wv [e][d], coalesced over t)
  const float ia = 1.f / asv;
  float u0 = 0.f, u1 = 0.f, u2 = 0.f, u3 = 0.f;
  #pragma unroll 8
  for (int e = 0; e < D_; e += 4) {
    u0 = fmaf(urs[e],     Wv[(size_t)(e)     * D_ + t], u0);
    u1 = fmaf(urs[e + 1], Wv[(size_t)(e + 1) * D_ + t], u1);
    u2 = fmaf(urs[e + 2], Wv[(size_t)(e + 2) * D_ + t], u2);
    u3 = fmaf(urs[e + 3], Wv[(size_t)(e + 3) * D_ + t], u3);
  }
  const float xv = (u0 + u1 + u2 + u3) * ia;
  xs[t] = xv;
  __syncthreads();
  float gi0 = bi[t], gi1 = bi[D_ + t], gi2 = bi[2 * D_ + t];
  float gh0 = bh[t], gh1 = bh[D_ + t], gh2 = bh[2 * D_ + t];
  #pragma unroll 8
  for (int d = 0; d < D_; ++d) {
    float xd = xs[d], hd = hs[d];
    const float* wid = wiT + d * 768;
    const float* whd = whT + d * 768;
    gi0 = fmaf(xd, wid[t], gi0); gi1 = fmaf(xd, wid[D_ + t], gi1); gi2 = fmaf(xd, wid[2 * D_ + t], gi2);
    gh0 = fmaf(hd, whd[t], gh0); gh1 = fmaf(hd, whd[D_ + t], gh1); gh2 = fmaf(hd, whd[2 * D_ + t], gh2);
  }
  float r = 1.f / (1.f + __expf(-(gi0 + gh0)));
  float z = 1.f / (1.f + __expf(-(gi1 + gh1)));
  float n = tanhf(gi2 + r * gh2);
  float hnew = (1.f - z) * n + z * hv;
  // LayerNorm(hnew) with ln_ff params
  float s1 = hnew, s2 = hnew * hnew;
  #pragma unroll
  for (int m = 32; m >= 1; m >>= 1) { s1 += __shfl_xor(s1, m, 64); s2 += __shfl_xor(s2, m, 64); }
  const int wave = t >> 6, lane = t & 63;
  if (lane == 0) { red1[wave] = s1; red2[wave] = s2; }
  __syncthreads();
  s1 = red1[0] + red1[1] + red1[2] + red1[3];
  s2 = red2[0] + red2[1] + red2[2] + red2[3];
  float mean = s1 * (1.f / D_);
  float rstd = rsqrtf(s2 * (1.f / D_) - mean * mean + LN_EPS_);
  ffs[t] = (hnew - mean) * rstd * gf[t] + bf[t];
  __syncthreads();
  float h1a = b1[t], h2a = b1[D_ + t], h1b = 0.f, h2b = 0.f;
  #pragma unroll 8
  for (int d = 0; d < D_; d += 2) {
    float f0 = ffs[d], f1 = ffs[d + 1];
    h1a = fmaf(f0, w1[(size_t)(d)     * HID_ + t],       h1a);
    h2a = fmaf(f0, w1[(size_t)(d)     * HID_ + D_ + t],  h2a);
    h1b = fmaf(f1, w1[(size_t)(d + 1) * HID_ + t],       h1b);
    h2b = fmaf(f1, w1[(size_t)(d + 1) * HID_ + D_ + t],  h2b);
  }
  hid[t] = fmaxf(h1a + h1b, 0.f); hid[D_ + t] = fmaxf(h2a + h2b, 0.f);
  __syncthreads();
  float oa = b2[t], ob = 0.f;
  #pragma unroll 8
  for (int d = 0; d < HID_; d += 2) {
    oa = fmaf(hid[d],     w2[(size_t)(d)     * D_ + t], oa);
    ob = fmaf(hid[d + 1], w2[(size_t)(d + 1) * D_ + t], ob);
  }
  const float o = oa + ob + hnew;
  out[(size_t)row * D_ + t] = o;

  // ---- next-iteration qk = LN_s(new slots) @ M (reuses this block's row) ----
  s1 = o; s2 = o * o;
  #pragma unroll
  for (int m = 32; m >= 1; m >>= 1) { s1 += __shfl_xor(s1, m, 64); s2 += __shfl_xor(s2, m, 64); }
  __syncthreads();   // red1/red2 reuse
  if (lane == 0) { red1[wave] = s1; red2[wave] = s2; }
  __syncthreads();
  s1 = red1[0] + red1[1] + red1[2] + red1[3];
  s2 = red2[0] + red2[1] + red2[2] + red2[3];
  mean = s1 * (1.f / D_);
  rstd = rsqrtf(s2 * (1.f / D_) - mean * mean + LN_EPS_);
  ffs[t] = (o - mean) * rstd * gs[t] + bs[t];
  __syncthreads();
  float a0 = 0.f, a1 = 0.f, a2 = 0.f, a3 = 0.f;
  #pragma unroll 8
  for (int d = 0; d < D_; d += 4) {
    a0 = fmaf(ffs[d],     M[(d)     * D_ + t], a0);
    a1 = fmaf(ffs[d + 1], M[(d + 1) * D_ + t], a1);
    a2 = fmaf(ffs[d + 2], M[(d + 2) * D_ + t], a2);
    a3 = fmaf(ffs[d + 3], M[(d + 3) * D_ + t], a3);
  }
  qk[(size_t)row * D_ + t] = a0 + a1 + a2 + a3;
}

extern "C" void kernel_launch(void* const* d_in, const int* in_sizes, int n_in,
                              void* d_out, int out_size, void* d_ws, size_t ws_size,
                              hipStream_t stream) {
  (void)in_sizes; (void)n_in; (void)out_size; (void)ws_size;
  const float* inputs = (const float*)d_in[0];
  const float* noise  = (const float*)d_in[1];
  const float* mu     = (const float*)d_in[2];
  const float* ls     = (const float*)d_in[3];
  const float* Wq     = (const float*)d_in[4];
  const float* Wk     = (const float*)d_in[5];
  const float* Wv     = (const float*)d_in[6];
  const float* gwi    = (const float*)d_in[7];
  const float* gwh    = (const float*)d_in[8];
  const float* gbi    = (const float*)d_in[9];
  const float* gbh    = (const float*)d_in[10];
  const float* w1     = (const float*)d_in[11];
  const float* b1     = (const float*)d_in[12];
  const float* w2     = (const float*)d_in[13];
  const float* b2     = (const float*)d_in[14];
  const float* gin    = (const float*)d_in[15];
  const float* bin    = (const float*)d_in[16];
  const float* gs     = (const float*)d_in[17];
  const float* bs     = (const float*)d_in[18];
  const float* gff    = (const float*)d_in[19];
  const float* bff    = (const float*)d_in[20];

  // workspace layout
  const size_t KV = (size_t)B_ * N_ * D_;        // 67.1M elems
  f16*   xh    = (f16*)d_ws;                     // 134 MB
  float* slots = (float*)(xh + KV);
  float* qk    = slots + (size_t)B_ * NS_ * D_;
  float* asum  = qk + (size_t)B_ * NS_ * D_;
  float* ur    = asum + 512;
  float* wiT   = ur + (size_t)B_ * NS_ * D_;
  float* whT   = wiT + 768 * 256;
  float* WkX   = whT + 768 * 256;
  float* M     = WkX + 256 * 256;

  k_wkx<<<256, 256, 0, stream>>>(Wk, WkX);
  k_m<<<256, 256, 0, stream>>>(Wq, WkX, M);
  k_transpose<<<768, 256, 0, stream>>>(gwi, gwh, wiT, whT);
  k_init_slots<<<512, 256, 0, stream>>>(noise, mu, ls, slots);
  k_xh<<<B_ * N_ / 4, 256, 0, stream>>>(inputs, gin, bin, xh);
  k_qk<<<512, 256, 0, stream>>>(slots, gs, bs, M, qk, ur, asum);
  for (int it = 0; it < 4; ++it) {
    k_attn_upd<<<dim3(32, 64), 256, 0, stream>>>(xh, qk, ur, asum);
    float* outp = (it == 3) ? (float*)d_out : slots;
    k_gru_mlp<<<512, 256, 0, stream>>>(ur, asum, slots, Wv, wiT, whT, gbi, gbh,
                                       w1, b1, w2, b2, gff, bff, gs, bs, M,
                                       outp, qk);
  }
}

// Round 12
// 843.530 us; speedup vs baseline: 2.2108x; 2.2108x over previous
//
#include <hip/hip_runtime.h>
#include <cstdint>

#define B_ 64
#define N_ 4096
#define D_ 256
#define NS_ 8
#define HID_ 512
#define TOK_ 128
#define EPS_ 1e-8f
#define SCALE_ 0.0625f
#define LN_EPS_ 1e-5f

typedef _Float16 f16;
typedef __attribute__((ext_vector_type(4))) _Float16 f16x4;
typedef __attribute__((ext_vector_type(8))) _Float16 f16x8;
typedef __attribute__((ext_vector_type(4))) float f32x4;

#define MFMA16(a, b, c) __builtin_amdgcn_mfma_f32_16x16x32_f16(a, b, c, 0, 0, 0)

// ---------------- transpose GRU weights [768][256] -> [256][768] ----------------
__global__ void k_transpose(const float* __restrict__ wi, const float* __restrict__ wh,
                            float* __restrict__ wiT, float* __restrict__ whT) {
  int idx = blockIdx.x * 256 + threadIdx.x;
  int o = idx >> 8;
  int d = idx & 255;
  wiT[d * 768 + o] = wi[idx];
  whT[d * 768 + o] = wh[idx];
}

// ---------------- transpose Wk [e][d] -> WkX [d][e] (fp32) ----------------
__global__ void k_wkx(const float* __restrict__ Wk, float* __restrict__ WkX) {
  int e = blockIdx.x, d = threadIdx.x;
  WkX[d * 256 + e] = Wk[e * 256 + d];
}

// ---------------- M[c][e] = SCALE * sum_d Wq[c][d] * Wk[e][d] ----------------
__global__ __launch_bounds__(256) void k_m(const float* __restrict__ Wq,
                                           const float* __restrict__ WkX,
                                           float* __restrict__ M) {
  __shared__ float wq[256];
  const int c = blockIdx.x, e = threadIdx.x;
  wq[e] = Wq[c * 256 + e];
  __syncthreads();
  float a0 = 0.f, a1 = 0.f, a2 = 0.f, a3 = 0.f;
  #pragma unroll 8
  for (int d = 0; d < 256; d += 4) {
    a0 = fmaf(wq[d],     WkX[(d)     * 256 + e], a0);
    a1 = fmaf(wq[d + 1], WkX[(d + 1) * 256 + e], a1);
    a2 = fmaf(wq[d + 2], WkX[(d + 2) * 256 + e], a2);
    a3 = fmaf(wq[d + 3], WkX[(d + 3) * 256 + e], a3);
  }
  M[c * 256 + e] = (a0 + a1 + a2 + a3) * SCALE_;
}

// ---------------- slots init ----------------
__global__ void k_init_slots(const float* __restrict__ noise, const float* __restrict__ mu,
                             const float* __restrict__ ls, float* __restrict__ slots) {
  int idx = blockIdx.x * 256 + threadIdx.x;
  int d = idx & 255;
  slots[idx] = mu[d] + __expf(ls[d]) * noise[idx];
}

// ---------------- xh = LN(inputs) as fp16 (wave per row) ----------------
__global__ __launch_bounds__(256) void k_xh(const float* __restrict__ in,
    const float* __restrict__ g, const float* __restrict__ bb, f16* __restrict__ xh) {
  const int wave = threadIdx.x >> 6, lane = threadIdx.x & 63;
  const size_t row = (size_t)blockIdx.x * 4 + wave;
  const float* r = in + row * D_;
  float4 a = *(const float4*)(r + lane * 4);
  float s1 = a.x + a.y + a.z + a.w;
  float s2 = a.x * a.x + a.y * a.y + a.z * a.z + a.w * a.w;
  #pragma unroll
  for (int m = 32; m >= 1; m >>= 1) { s1 += __shfl_xor(s1, m, 64); s2 += __shfl_xor(s2, m, 64); }
  const float mean = s1 * (1.f / D_);
  const float rstd = rsqrtf(s2 * (1.f / D_) - mean * mean + LN_EPS_);
  float4 gg = *(const float4*)(g + lane * 4);
  float4 bv = *(const float4*)(bb + lane * 4);
  f16x4 o;
  o[0] = (f16)((a.x - mean) * rstd * gg.x + bv.x);
  o[1] = (f16)((a.y - mean) * rstd * gg.y + bv.y);
  o[2] = (f16)((a.z - mean) * rstd * gg.z + bv.z);
  o[3] = (f16)((a.w - mean) * rstd * gg.w + bv.w);
  *(f16x4*)(xh + row * D_ + lane * 4) = o;
}

// ---------------- qkh = f16( LN(slots) @ M ) + zero ur/asum (once, before iter 0) ----
__global__ __launch_bounds__(256) void k_qk(const float* __restrict__ slots,
    const float* __restrict__ g, const float* __restrict__ b,
    const float* __restrict__ M, f16* __restrict__ qkh,
    float* __restrict__ ur, float* __restrict__ asum) {
  const int row = blockIdx.x;
  const int t = threadIdx.x;
  ur[(size_t)row * D_ + t] = 0.f;
  if (t == 0) asum[row] = 0.f;
  __shared__ float sl[256];
  __shared__ float red1[4], red2[4];
  float val = slots[(size_t)row * D_ + t];
  float s1 = val, s2 = val * val;
  #pragma unroll
  for (int m = 32; m >= 1; m >>= 1) { s1 += __shfl_xor(s1, m, 64); s2 += __shfl_xor(s2, m, 64); }
  int wave = t >> 6, lane = t & 63;
  if (lane == 0) { red1[wave] = s1; red2[wave] = s2; }
  __syncthreads();
  s1 = red1[0] + red1[1] + red1[2] + red1[3];
  s2 = red2[0] + red2[1] + red2[2] + red2[3];
  float mean = s1 * (1.f / D_);
  float rstd = rsqrtf(s2 * (1.f / D_) - mean * mean + LN_EPS_);
  sl[t] = (val - mean) * rstd * g[t] + b[t];
  __syncthreads();
  float a0 = 0.f, a1 = 0.f, a2 = 0.f, a3 = 0.f;
  #pragma unroll 8
  for (int d = 0; d < D_; d += 4) {
    a0 = fmaf(sl[d],     M[(d)     * D_ + t], a0);
    a1 = fmaf(sl[d + 1], M[(d + 1) * D_ + t], a1);
    a2 = fmaf(sl[d + 2], M[(d + 2) * D_ + t], a2);
    a3 = fmaf(sl[d + 3], M[(d + 3) * D_ + t], a3);
  }
  qkh[((size_t)(row >> 3) * 16 + (row & 7)) * D_ + t] = (f16)(a0 + a1 + a2 + a3);
}

// ---------------- MFMA attention: dots + softmax + asum + u_raw ----------------
// 256 thr / 128 tokens. LDS: swizzled xh tile (64KB) + qk 16-row pad (8KB) + wv (6KB).
// Phase A: mfma(qk[16x32], xh[32x16]) per N-tile -> softmax via shfl_xor(16).
// Phase B: wave-per-2-slots VALU accumulation from the LDS tile.
__global__ __launch_bounds__(256) void k_attn_upd(
    const f16* __restrict__ xh, const f16* __restrict__ qkh,
    float* __restrict__ ur, float* __restrict__ asum) {
  __shared__ __align__(16) f16 xt[TOK_ * 256];   // 64 KB, chunk-swizzled
  __shared__ __align__(16) f16 qs[16 * 256];     // 8 KB, chunk-swizzled (rows 8-15 = pad)
  __shared__ float wv_s[TOK_ * 12];              // 6 KB (pad 12 -> float4-aligned halves)
  const int b = blockIdx.y;
  const int jt = blockIdx.x * TOK_;
  const int tid = threadIdx.x;
  const int wave = tid >> 6, lane = tid & 63;

  // ---- stage qs: thread -> (row=tid>>4, two 8-f16 chunks), XOR-swizzle chunks ----
  {
    const int r = tid >> 4, c0 = (tid & 15) * 2;
    const f16* src = qkh + ((size_t)b * 16 + r) * D_;
    *(f16x8*)&qs[r * 256 + ((c0)     ^ (r & 7)) * 8] = *(const f16x8*)(src + c0 * 8);
    *(f16x8*)&qs[r * 256 + ((c0 + 1) ^ (r & 7)) * 8] = *(const f16x8*)(src + c0 * 8 + 8);
  }
  // ---- stage xt: 16 rounds x 4KB, loads fully coalesced, swizzled ds_write ----
  {
    const f16* src = xh + ((size_t)b * N_ + jt) * D_;
    f16x8 v[16];
    #pragma unroll
    for (int i = 0; i < 16; ++i) {
      const int r = i * 8 + (tid >> 5), c = tid & 31;
      v[i] = *(const f16x8*)(src + r * 256 + c * 8);
    }
    #pragma unroll
    for (int i = 0; i < 16; ++i) {
      const int r = i * 8 + (tid >> 5), c = tid & 31;
      *(f16x8*)&xt[r * 256 + (c ^ (r & 7)) * 8] = v[i];
    }
  }
  __syncthreads();

  // ---- phase A: MFMA dots; A-frags (qk) loaded once ----
  const int kg = lane >> 4;            // k-group 0..3
  f16x8 afr[8];
  {
    const int arow = lane & 15;
    #pragma unroll
    for (int kk = 0; kk < 8; ++kk)
      afr[kk] = *(const f16x8*)&qs[arow * 256 + ((kk * 4 + kg) ^ (arow & 7)) * 8];
  }
  float tsum0 = 0.f, tsum1 = 0.f, tsum2 = 0.f, tsum3 = 0.f;
  #pragma unroll
  for (int t2 = 0; t2 < 2; ++t2) {
    const int nt = wave * 2 + t2;
    const int tok = nt * 16 + (lane & 15);   // block-local token, also B-frag col
    f32x4 acc = {0.f, 0.f, 0.f, 0.f};
    #pragma unroll
    for (int kk = 0; kk < 8; ++kk) {
      f16x8 bf = *(const f16x8*)&xt[tok * 256 + ((kk * 4 + kg) ^ (tok & 7)) * 8];
      acc = MFMA16(afr[kk], bf, acc);
    }
    // lane (l<16): slots 0-3 of token; lane+16: slots 4-7. Exchange and softmax.
    float o0 = __shfl_xor(acc[0], 16, 64);
    float o1 = __shfl_xor(acc[1], 16, 64);
    float o2 = __shfl_xor(acc[2], 16, 64);
    float o3 = __shfl_xor(acc[3], 16, 64);
    if (lane < 32) {
      float m = fmaxf(fmaxf(fmaxf(acc[0], acc[1]), fmaxf(acc[2], acc[3])),
                      fmaxf(fmaxf(o0, o1), fmaxf(o2, o3)));
      float e0 = __expf(acc[0] - m), e1 = __expf(acc[1] - m);
      float e2 = __expf(acc[2] - m), e3 = __expf(acc[3] - m);
      float sm = e0 + e1 + e2 + e3;
      float so = __shfl_xor(sm, 16, 64);
      float inv = 1.f / (sm + so);
      float4 wv;
      wv.x = e0 * inv + EPS_; wv.y = e1 * inv + EPS_;
      wv.z = e2 * inv + EPS_; wv.w = e3 * inv + EPS_;
      *(float4*)&wv_s[tok * 12 + (lane >> 4) * 4] = wv;
      // reduce over the 16 tokens of this N-tile (lanes 0-15 / 16-31 groups)
      float r0 = wv.x, r1 = wv.y, r2 = wv.z, r3 = wv.w;
      #pragma unroll
      for (int mm = 1; mm <= 8; mm <<= 1) {
        r0 += __shfl_xor(r0, mm, 64); r1 += __shfl_xor(r1, mm, 64);
        r2 += __shfl_xor(r2, mm, 64); r3 += __shfl_xor(r3, mm, 64);
      }
      tsum0 += r0; tsum1 += r1; tsum2 += r2; tsum3 += r3;
    }
  }
  if (lane == 0 || lane == 16) {
    const int sb = (lane >> 4) * 4;
    atomicAdd(&asum[b * NS_ + sb + 0], tsum0);
    atomicAdd(&asum[b * NS_ + sb + 1], tsum1);
    atomicAdd(&asum[b * NS_ + sb + 2], tsum2);
    atomicAdd(&asum[b * NS_ + sb + 3], tsum3);
  }
  __syncthreads();

  // ---- phase B: wave -> slots (2w, 2w+1); lane -> d-quad lane*4; read LDS tile ----
  {
    const int i0 = wave * 2;
    const int ch0 = lane >> 1, sub = (lane & 1) * 4;
    float a0[4] = {0.f, 0.f, 0.f, 0.f};
    float a1[4] = {0.f, 0.f, 0.f, 0.f};
    #pragma unroll 4
    for (int j = 0; j < TOK_; ++j) {
      f16x4 v = *(const f16x4*)&xt[j * 256 + (ch0 ^ (j & 7)) * 8 + sub];
      float vx = (float)v[0], vy = (float)v[1], vz = (float)v[2], vw = (float)v[3];
      float w0 = wv_s[j * 12 + i0];
      float w1 = wv_s[j * 12 + i0 + 1];
      a0[0] = fmaf(w0, vx, a0[0]); a0[1] = fmaf(w0, vy, a0[1]);
      a0[2] = fmaf(w0, vz, a0[2]); a0[3] = fmaf(w0, vw, a0[3]);
      a1[0] = fmaf(w1, vx, a1[0]); a1[1] = fmaf(w1, vy, a1[1]);
      a1[2] = fmaf(w1, vz, a1[2]); a1[3] = fmaf(w1, vw, a1[3]);
    }
    float* u0 = ur + ((size_t)b * NS_ + i0) * D_ + lane * 4;
    float* u1 = u0 + D_;
    #pragma unroll
    for (int c = 0; c < 4; ++c) { atomicAdd(u0 + c, a0[c]); atomicAdd(u1 + c, a1[c]); }
  }
}

// ---------------- GRU + LN + MLP residual + next-iter qkh + accumulator zero ----------------
__global__ __launch_bounds__(256) void k_gru_mlp(
    float* __restrict__ ur, float* __restrict__ asum,
    const float* __restrict__ slots, const float* __restrict__ Wv,
    const float* __restrict__ wiT, const float* __restrict__ whT,
    const float* __restrict__ bi, const float* __restrict__ bh,
    const float* __restrict__ w1, const float* __restrict__ b1,
    const float* __restrict__ w2, const float* __restrict__ b2,
    const float* __restrict__ gf, const float* __restrict__ bf,
    const float* __restrict__ gs, const float* __restrict__ bs,
    const float* __restrict__ M,
    float* __restrict__ out, f16* __restrict__ qkh) {
  const int row = blockIdx.x;   // 0..511 = b*8+i
  const int t = threadIdx.x;
  __shared__ float urs[256], xs[256], hs[256], ffs[256], hid[512];
  __shared__ float red1[4], red2[4];
  const float hv = slots[(size_t)row * D_ + t];
  const float asv = asum[row];
  urs[t] = ur[(size_t)row * D_ + t];
  ur[(size_t)row * D_ + t] = 0.f;
  hs[t] = hv;
  __syncthreads();
  if (t == 0) asum[row] = 0.f;
  const float ia = 1.f / asv;
  float u0 = 0.f, u1 = 0.f, u2 = 0.f, u3 = 0.f;
  #pragma unroll 8
  for (int e = 0; e < D_; e += 4) {
    u0 = fmaf(urs[e],     Wv[(size_t)(e)     * D_ + t], u0);
    u1 = fmaf(urs[e + 1], Wv[(size_t)(e + 1) * D_ + t], u1);
    u2 = fmaf(urs[e + 2], Wv[(size_t)(e + 2) * D_ + t], u2);
    u3 = fmaf(urs[e + 3], Wv[(size_t)(e + 3) * D_ + t], u3);
  }
  const float xv = (u0 + u1 + u2 + u3) * ia;
  xs[t] = xv;
  __syncthreads();
  float gi0 = bi[t], gi1 = bi[D_ + t], gi2 = bi[2 * D_ + t];
  float gh0 = bh[t], gh1 = bh[D_ + t], gh2 = bh[2 * D_ + t];
  #pragma unroll 8
  for (int d = 0; d < D_; ++d) {
    float xd = xs[d], hd = hs[d];
    const float* wid = wiT + d * 768;
    const float* whd = whT + d * 768;
    gi0 = fmaf(xd, wid[t], gi0); gi1 = fmaf(xd, wid[D_ + t], gi1); gi2 = fmaf(xd, wid[2 * D_ + t], gi2);
    gh0 = fmaf(hd, whd[t], gh0); gh1 = fmaf(hd, whd[D_ + t], gh1); gh2 = fmaf(hd, whd[2 * D_ + t], gh2);
  }
  float r = 1.f / (1.f + __expf(-(gi0 + gh0)));
  float z = 1.f / (1.f + __expf(-(gi1 + gh1)));
  float n = tanhf(gi2 + r * gh2);
  float hnew = (1.f - z) * n + z * hv;
  float s1 = hnew, s2 = hnew * hnew;
  #pragma unroll
  for (int m = 32; m >= 1; m >>= 1) { s1 += __shfl_xor(s1, m, 64); s2 += __shfl_xor(s2, m, 64); }
  const int wave = t >> 6, lane = t & 63;
  if (lane == 0) { red1[wave] = s1; red2[wave] = s2; }
  __syncthreads();
  s1 = red1[0] + red1[1] + red1[2] + red1[3];
  s2 = red2[0] + red2[1] + red2[2] + red2[3];
  float mean = s1 * (1.f / D_);
  float rstd = rsqrtf(s2 * (1.f / D_) - mean * mean + LN_EPS_);
  ffs[t] = (hnew - mean) * rstd * gf[t] + bf[t];
  __syncthreads();
  float h1a = b1[t], h2a = b1[D_ + t], h1b = 0.f, h2b = 0.f;
  #pragma unroll 8
  for (int d = 0; d < D_; d += 2) {
    float f0 = ffs[d], f1 = ffs[d + 1];
    h1a = fmaf(f0, w1[(size_t)(d)     * HID_ + t],       h1a);
    h2a = fmaf(f0, w1[(size_t)(d)     * HID_ + D_ + t],  h2a);
    h1b = fmaf(f1, w1[(size_t)(d + 1) * HID_ + t],       h1b);
    h2b = fmaf(f1, w1[(size_t)(d + 1) * HID_ + D_ + t],  h2b);
  }
  hid[t] = fmaxf(h1a + h1b, 0.f); hid[D_ + t] = fmaxf(h2a + h2b, 0.f);
  __syncthreads();
  float oa = b2[t], ob = 0.f;
  #pragma unroll 8
  for (int d = 0; d < HID_; d += 2) {
    oa = fmaf(hid[d],     w2[(size_t)(d)     * D_ + t], oa);
    ob = fmaf(hid[d + 1], w2[(size_t)(d + 1) * D_ + t], ob);
  }
  const float o = oa + ob + hnew;
  out[(size_t)row * D_ + t] = o;

  // ---- next-iteration qkh = f16( LN_s(new slots) @ M ) ----
  s1 = o; s2 = o * o;
  #pragma unroll
  for (int m = 32; m >= 1; m >>= 1) { s1 += __shfl_xor(s1, m, 64); s2 += __shfl_xor(s2, m, 64); }
  __syncthreads();
  if (lane == 0) { red1[wave] = s1; red2[wave] = s2; }
  __syncthreads();
  s1 = red1[0] + red1[1] + red1[2] + red1[3];
  s2 = red2[0] + red2[1] + red2[2] + red2[3];
  mean = s1 * (1.f / D_);
  rstd = rsqrtf(s2 * (1.f / D_) - mean * mean + LN_EPS_);
  ffs[t] = (o - mean) * rstd * gs[t] + bs[t];
  __syncthreads();
  float a0 = 0.f, a1 = 0.f, a2 = 0.f, a3 = 0.f;
  #pragma unroll 8
  for (int d = 0; d < D_; d += 4) {
    a0 = fmaf(ffs[d],     M[(d)     * D_ + t], a0);
    a1 = fmaf(ffs[d + 1], M[(d + 1) * D_ + t], a1);
    a2 = fmaf(ffs[d + 2], M[(d + 2) * D_ + t], a2);
    a3 = fmaf(ffs[d + 3], M[(d + 3) * D_ + t], a3);
  }
  qkh[((size_t)(row >> 3) * 16 + (row & 7)) * D_ + t] = (f16)(a0 + a1 + a2 + a3);
}

extern "C" void kernel_launch(void* const* d_in, const int* in_sizes, int n_in,
                              void* d_out, int out_size, void* d_ws, size_t ws_size,
                              hipStream_t stream) {
  (void)in_sizes; (void)n_in; (void)out_size; (void)ws_size;
  const float* inputs = (const float*)d_in[0];
  const float* noise  = (const float*)d_in[1];
  const float* mu     = (const float*)d_in[2];
  const float* ls     = (const float*)d_in[3];
  const float* Wq     = (const float*)d_in[4];
  const float* Wk     = (const float*)d_in[5];
  const float* Wv     = (const float*)d_in[6];
  const float* gwi    = (const float*)d_in[7];
  const float* gwh    = (const float*)d_in[8];
  const float* gbi    = (const float*)d_in[9];
  const float* gbh    = (const float*)d_in[10];
  const float* w1     = (const float*)d_in[11];
  const float* b1     = (const float*)d_in[12];
  const float* w2     = (const float*)d_in[13];
  const float* b2     = (const float*)d_in[14];
  const float* gin    = (const float*)d_in[15];
  const float* bin    = (const float*)d_in[16];
  const float* gs     = (const float*)d_in[17];
  const float* bs     = (const float*)d_in[18];
  const float* gff    = (const float*)d_in[19];
  const float* bff    = (const float*)d_in[20];

  // workspace layout
  const size_t KV = (size_t)B_ * N_ * D_;
  f16*   xh    = (f16*)d_ws;                         // 134 MB
  float* slots = (float*)(xh + KV);
  f16*   qkh   = (f16*)(slots + (size_t)B_ * NS_ * D_);   // 64x16x256 f16
  float* asum  = (float*)(qkh + (size_t)B_ * 16 * D_);
  float* ur    = asum + 512;
  float* wiT   = ur + (size_t)B_ * NS_ * D_;
  float* whT   = wiT + 768 * 256;
  float* WkX   = whT + 768 * 256;
  float* M     = WkX + 256 * 256;

  k_wkx<<<256, 256, 0, stream>>>(Wk, WkX);
  k_m<<<256, 256, 0, stream>>>(Wq, WkX, M);
  k_transpose<<<768, 256, 0, stream>>>(gwi, gwh, wiT, whT);
  k_init_slots<<<512, 256, 0, stream>>>(noise, mu, ls, slots);
  k_xh<<<B_ * N_ / 4, 256, 0, stream>>>(inputs, gin, bin, xh);
  k_qk<<<512, 256, 0, stream>>>(slots, gs, bs, M, qkh, ur, asum);
  for (int it = 0; it < 4; ++it) {
    k_attn_upd<<<dim3(N_ / TOK_, B_), 256, 0, stream>>>(xh, qkh, ur, asum);
    float* outp = (it == 3) ? (float*)d_out : slots;
    k_gru_mlp<<<512, 256, 0, stream>>>(ur, asum, slots, Wv, wiT, whT, gbi, gbh,
                                       w1, b1, w2, b2, gff, bff, gs, bs, M,
                                       outp, qkh);
  }
}